// Round 6
// baseline (316.753 us; speedup 1.0000x reference)
//
#include <hip/hip_runtime.h>

// ProbsNet: out = mean over 5 of [p_m @ tmp_{0 or 1}]
//   tmp_t[i] = sum_d sigmoid(pB*(pBEV*BEV + ST_t[i,d])) * W_t[i,d]
//
// R11: post-'nt' regime, all read-supply levers swept to null (R4 depth,
// R5 stream geometry). Remaining controllable cost: the 1-block reduce
// dispatch = pure serialized launch latency. This round: single dispatch.
// Last-block-done ticket (rocPRIM pattern): every block atomicExch-stores
// its pre-weighted partial, __threadfence, atomicAdd ticket; last block
// re-fences and sums partials in FIXED index order (deterministic), writes
// out. Ticket zeroed per launch by captured hipMemsetAsync.
// Shape: R4 (tied-best) = 2688 blocks, 2 chunks x 1024 f4, counted
// overlap vmcnt(8)/vmcnt(0), nt loads.

#define D_DIM         131072
#define N_ROWS        84
#define ROW_F4        (D_DIM / 4)                   // 32768 float4 per row
#define TENSOR_F4     (N_ROWS * ROW_F4)             // 2752512 float4 per tensor
#define F4_PER_BLOCK  2048                          // 2 chunks of 1024
#define T0_BLOCKS     (TENSOR_F4 / F4_PER_BLOCK)    // 1344
#define BLOCKS        (2 * T0_BLOCKS)               // 2688 = 10.5 blocks/CU

typedef float f32x4 __attribute__((ext_vector_type(4)));

// entry t of calc_probs(logits): i=t/21; r=t%21
//   r==0 -> p_i ; else r-=1, j=r/5, s=r%5: s==0 -> p_i*p_j else p_i*p_j*p_{s-1}
__device__ inline float prob_entry(const float* __restrict__ logits, int t) {
    float l0 = logits[0], l1 = logits[1], l2 = logits[2], l3 = logits[3];
    float m  = fmaxf(fmaxf(l0, l1), fmaxf(l2, l3));
    float e0 = __expf(l0 - m), e1 = __expf(l1 - m);
    float e2 = __expf(l2 - m), e3 = __expf(l3 - m);
    float inv = 1.0f / (e0 + e1 + e2 + e3);
    float p[4] = {e0 * inv, e1 * inv, e2 * inv, e3 * inv};
    int i = t / 21;
    int r = t - i * 21;
    if (r == 0) return p[i];
    r -= 1;
    int j = r / 5;
    int s = r - j * 5;
    float v = p[i] * p[j];
    return (s == 0) ? v : v * p[s - 1];
}

// w * sigmoid(pb*(bev+s)) = w * rcp(1 + exp2(a*s + ab)), a = -pb*log2(e)
__device__ inline float sigdot(float w, float s, float a, float ab) {
    float e = __builtin_amdgcn_exp2f(fmaf(a, s, ab));
    return w * __builtin_amdgcn_rcpf(1.0f + e);
}

// 8 x 16B nt loads (4 S + 4 W) via SGPR base + 32-bit voffset. Separate
// volatile asm blocks keep mutual program order -> vmcnt counts are exact.
#define ISSUE8(S0, S1, S2, S3, Wa, Wb_, Wc, Wd, OFFC)                      \
    asm volatile(                                                          \
        "global_load_dwordx4 %0, %8, %12 nt\n\t"                           \
        "global_load_dwordx4 %4, %8, %13 nt\n\t"                           \
        "global_load_dwordx4 %1, %9, %12 nt\n\t"                           \
        "global_load_dwordx4 %5, %9, %13 nt\n\t"                           \
        "global_load_dwordx4 %2, %10, %12 nt\n\t"                          \
        "global_load_dwordx4 %6, %10, %13 nt\n\t"                          \
        "global_load_dwordx4 %3, %11, %12 nt\n\t"                          \
        "global_load_dwordx4 %7, %11, %13 nt"                              \
        : "=&v"(S0), "=&v"(S1), "=&v"(S2), "=&v"(S3),                      \
          "=&v"(Wa), "=&v"(Wb_), "=&v"(Wc), "=&v"(Wd)                      \
        : "v"(vbase + (OFFC) + 0u),    "v"(vbase + (OFFC) + 4096u),        \
          "v"(vbase + (OFFC) + 8192u), "v"(vbase + (OFFC) + 12288u),       \
          "s"(Sb), "s"(Wb))

// Wait until <=N vector loads outstanding; "+v" deps forbid hoisting
// consumers of these regs above the wait (rule #18 via dataflow).
#define WAITP(N, S0, S1, S2, S3, Wa, Wb_, Wc, Wd)                          \
    asm volatile("s_waitcnt vmcnt(%8)"                                     \
                 : "+v"(S0), "+v"(S1), "+v"(S2), "+v"(S3),                 \
                   "+v"(Wa), "+v"(Wb_), "+v"(Wc), "+v"(Wd) : "n"(N))

#define ACC16(S0, S1, S2, S3, Wa, Wb_, Wc, Wd)                             \
    do {                                                                   \
        acc += sigdot(Wa[0], S0[0], a, ab);                                \
        acc += sigdot(Wa[1], S0[1], a, ab);                                \
        acc += sigdot(Wa[2], S0[2], a, ab);                                \
        acc += sigdot(Wa[3], S0[3], a, ab);                                \
        acc += sigdot(Wb_[0], S1[0], a, ab);                               \
        acc += sigdot(Wb_[1], S1[1], a, ab);                               \
        acc += sigdot(Wb_[2], S1[2], a, ab);                               \
        acc += sigdot(Wb_[3], S1[3], a, ab);                               \
        acc += sigdot(Wc[0], S2[0], a, ab);                                \
        acc += sigdot(Wc[1], S2[1], a, ab);                                \
        acc += sigdot(Wc[2], S2[2], a, ab);                                \
        acc += sigdot(Wc[3], S2[3], a, ab);                                \
        acc += sigdot(Wd[0], S3[0], a, ab);                                \
        acc += sigdot(Wd[1], S3[1], a, ab);                                \
        acc += sigdot(Wd[2], S3[2], a, ab);                                \
        acc += sigdot(Wd[3], S3[3], a, ab);                                \
    } while (0)

__global__ __launch_bounds__(256, 4) void probsnet_main(
    const float* __restrict__ BEV,
    const float* __restrict__ ST0, const float* __restrict__ W0,
    const float* __restrict__ ST1, const float* __restrict__ W1,
    const float* __restrict__ probs0, const float* __restrict__ probs1,
    const float* __restrict__ probs2, const float* __restrict__ probs3,
    const float* __restrict__ probs4,
    const float* __restrict__ pBEV, const float* __restrict__ pB,
    float* __restrict__ partials, unsigned* __restrict__ ticket,
    float* __restrict__ out)
{
    const int bid    = blockIdx.x;
    const int t      = threadIdx.x;
    const int tensor = (bid >= T0_BLOCKS) ? 1 : 0;
    const int fb     = (bid - tensor * T0_BLOCKS) * F4_PER_BLOCK;
    const int row    = fb >> 15;                    // single row per block

    const float pb  = pB[0];
    const float bev = pBEV[0] * BEV[0];
    const float a   = -pb * 1.4426950408889634f;    // -pb*log2(e)
    const float ab  = a * bev;

    const float* Sb = tensor ? ST1 : ST0;
    const float* Wb = tensor ? W1  : W0;

    // byte offset of this thread's first float4 within the tensor
    const unsigned vbase = (unsigned)(fb + t) * 16u;

    f32x4 as0, as1, as2, as3, aw0, aw1, aw2, aw3;   // chunk A
    f32x4 bs0, bs1, bs2, bs3, bw0, bw1, bw2, bw3;   // chunk B

    ISSUE8(as0, as1, as2, as3, aw0, aw1, aw2, aw3, 0u);
    ISSUE8(bs0, bs1, bs2, bs3, bw0, bw1, bw2, bw3, 16384u);

    float acc = 0.0f;

    WAITP(8, as0, as1, as2, as3, aw0, aw1, aw2, aw3);   // A ready, B in flight
    ACC16(as0, as1, as2, as3, aw0, aw1, aw2, aw3);

    WAITP(0, bs0, bs1, bs2, bs3, bw0, bw1, bw2, bw3);   // B ready
    ACC16(bs0, bs1, bs2, bs3, bw0, bw1, bw2, bw3);

    // wave64 shuffle reduction
    #pragma unroll
    for (int off = 32; off > 0; off >>= 1)
        acc += __shfl_down(acc, off, 64);

    __shared__ float red[4];
    __shared__ int   is_last;
    const int wave = t >> 6;
    const int lane = t & 63;
    if (lane == 0) red[wave] = acc;
    __syncthreads();

    if (t == 0) {
        const float S = red[0] + red[1] + red[2] + red[3];
        float pw;
        if (tensor == 0) {
            pw = prob_entry(probs0, row);
        } else {
            pw = prob_entry(probs1, row) + prob_entry(probs2, row)
               + prob_entry(probs3, row) + prob_entry(probs4, row);
        }
        // coherent store of the pre-scaled partial, release, take a ticket
        atomicExch(&partials[bid], pw * S * 0.2f);
        __threadfence();
        const unsigned old = atomicAdd(ticket, 1u);
        is_last = (old == (unsigned)(BLOCKS - 1)) ? 1 : 0;
        if (is_last) __threadfence();   // acquire before reading partials
    }
    __syncthreads();

    if (is_last) {
        // Fixed index order regardless of WHICH block runs this ->
        // bitwise-deterministic final sum.
        float acc2 = 0.0f;
        for (int k = t; k < BLOCKS; k += 256)
            acc2 += partials[k];

        #pragma unroll
        for (int off = 32; off > 0; off >>= 1)
            acc2 += __shfl_down(acc2, off, 64);

        if (lane == 0) red[wave] = acc2;
        __syncthreads();

        if (t == 0)
            out[0] = red[0] + red[1] + red[2] + red[3];
    }
}

extern "C" void kernel_launch(void* const* d_in, const int* in_sizes, int n_in,
                              void* d_out, int out_size, void* d_ws, size_t ws_size,
                              hipStream_t stream) {
    // setup_inputs order:
    // 0=BEV(1) 1=ST0 2=Weight0 3=ST1 4=Weight1 5=Problem(int,unused)
    // 6..10=probs0..probs4(4) 11=pBEV(1) 12=pB(1)
    const float* BEV    = (const float*)d_in[0];
    const float* ST0    = (const float*)d_in[1];
    const float* W0     = (const float*)d_in[2];
    const float* ST1    = (const float*)d_in[3];
    const float* W1     = (const float*)d_in[4];
    const float* probs0 = (const float*)d_in[6];
    const float* probs1 = (const float*)d_in[7];
    const float* probs2 = (const float*)d_in[8];
    const float* probs3 = (const float*)d_in[9];
    const float* probs4 = (const float*)d_in[10];
    const float* pBEV   = (const float*)d_in[11];
    const float* pB     = (const float*)d_in[12];

    float*    partials = (float*)d_ws;               // 2688 floats
    unsigned* ticket   = (unsigned*)d_ws + BLOCKS;   // 1 uint after partials
    float*    out      = (float*)d_out;

    // zero the ticket each launch (captured into the graph; memsetAsync is
    // capture-safe — the harness's own reset() enqueues memsets)
    hipMemsetAsync(ticket, 0, sizeof(unsigned), stream);

    probsnet_main<<<BLOCKS, 256, 0, stream>>>(
        BEV, ST0, W0, ST1, W1,
        probs0, probs1, probs2, probs3, probs4,
        pBEV, pB, partials, ticket, out);
}

// Round 8
// 184.438 us; speedup vs baseline: 1.7174x; 1.7174x over previous
//
#include <hip/hip_runtime.h>

// ProbsNet: out = mean over 5 of [p_m @ tmp_{0 or 1}]
//   tmp_t[i] = sum_d sigmoid(pB*(pBEV*BEV + ST_t[i,d])) * W_t[i,d]
//
// R13: resubmit of R12 (= R5, session best 186.3us) after an
// infrastructure-only bench failure (container died twice; no kernel
// signal). No changes — keeping the A/B ledger clean.
// Session ledger: 'nt' loads = the one real win (201->187us, broke the
// L2/L3 allocation-thrash wall). Depth/turnover (R1/R4), stream geometry
// (R5), dispatch fusion (R6, -130us: per-block device fence = 2688 XCD-L2
// shootdowns): all null or negative with mechanism understood.

#define D_DIM           131072
#define N_ROWS          84
#define TASKS_PER_BLOCK 21        // 2*84*32 tasks / 256 blocks
#define BLOCKS          256
#define TASK_BYTES      16384     // 1024 float4 per task per array

typedef float f32x4 __attribute__((ext_vector_type(4)));

// entry t of calc_probs(logits): i=t/21; r=t%21
//   r==0 -> p_i ; else r-=1, j=r/5, s=r%5: s==0 -> p_i*p_j else p_i*p_j*p_{s-1}
__device__ inline float prob_entry(const float* __restrict__ logits, int t) {
    float l0 = logits[0], l1 = logits[1], l2 = logits[2], l3 = logits[3];
    float m  = fmaxf(fmaxf(l0, l1), fmaxf(l2, l3));
    float e0 = __expf(l0 - m), e1 = __expf(l1 - m);
    float e2 = __expf(l2 - m), e3 = __expf(l3 - m);
    float inv = 1.0f / (e0 + e1 + e2 + e3);
    float p[4] = {e0 * inv, e1 * inv, e2 * inv, e3 * inv};
    int i = t / 21;
    int r = t - i * 21;
    if (r == 0) return p[i];
    r -= 1;
    int j = r / 5;
    int s = r - j * 5;
    float v = p[i] * p[j];
    return (s == 0) ? v : v * p[s - 1];
}

// w * sigmoid(pb*(bev+s)) = w * rcp(1 + exp2(a*s + ab)), a = -pb*log2(e)
__device__ inline float sigdot(float w, float s, float a, float ab) {
    float e = __builtin_amdgcn_exp2f(fmaf(a, s, ab));
    return w * __builtin_amdgcn_rcpf(1.0f + e);
}

// Issue one (S,W) 16B nt load pair at byte offset vbase+OFFC from SGPR
// bases. volatile asm blocks keep mutual program order -> vmcnt exact.
#define ISSUE(SX, WX, OFFC)                                                \
    asm volatile("global_load_dwordx4 %0, %4, %2 nt\n\t"                   \
                 "global_load_dwordx4 %1, %4, %3 nt"                       \
                 : "=&v"(SX), "=&v"(WX)                                    \
                 : "s"(Sb), "s"(Wb), "v"(vbase + (unsigned)(OFFC)))

// Wait until <=N vector loads outstanding; "+v" deps stop the compiler
// from hoisting consumers of SX/WX above the wait (rule #18 via dataflow).
#define WAITP(N, SX, WX)                                                   \
    asm volatile("s_waitcnt vmcnt(%2)"                                     \
                 : "+v"(SX), "+v"(WX) : "n"(N))

#define ACC8(SX, WX)                                                       \
    do {                                                                   \
        acc_t += sigdot(WX[0], SX[0], a, ab);                              \
        acc_t += sigdot(WX[1], SX[1], a, ab);                              \
        acc_t += sigdot(WX[2], SX[2], a, ab);                              \
        acc_t += sigdot(WX[3], SX[3], a, ab);                              \
    } while (0)

// One pipeline step: wait for this slot's pair, consume it, re-issue the
// slot for task J+2 (same k). ISS=0 in the epilogue (no more issues).
#define STEP(SX, WX, N, ISS, OFFC)                                         \
    do {                                                                   \
        WAITP(N, SX, WX);                                                  \
        ACC8(SX, WX);                                                      \
        if (ISS) { ISSUE(SX, WX, OFFC); }                                  \
    } while (0)

// Task J: 4 steps (k=0..3) + fold the per-row prob weight.
#define TASK(J, A0,B0,A1,B1,A2,B2,A3,B3, N0,N1,N2,N3, ISS)                 \
    do {                                                                   \
        const int   row_ = (tb21 + (J)) >> 5;                              \
        const float pw_  = (row_ == r0) ? pw0 : pw1;                       \
        float acc_t = 0.0f;                                                \
        STEP(A0, B0, N0, ISS, ((J) + 2) * TASK_BYTES + 0 * 1024);          \
        STEP(A1, B1, N1, ISS, ((J) + 2) * TASK_BYTES + 1 * 1024);          \
        STEP(A2, B2, N2, ISS, ((J) + 2) * TASK_BYTES + 2 * 1024);          \
        STEP(A3, B3, N3, ISS, ((J) + 2) * TASK_BYTES + 3 * 1024);          \
        acc = fmaf(pw_, acc_t, acc);                                       \
    } while (0)

__global__ __launch_bounds__(256, 1) void probsnet_main(
    const float* __restrict__ BEV,
    const float* __restrict__ ST0, const float* __restrict__ W0,
    const float* __restrict__ ST1, const float* __restrict__ W1,
    const float* __restrict__ probs0, const float* __restrict__ probs1,
    const float* __restrict__ probs2, const float* __restrict__ probs3,
    const float* __restrict__ probs4,
    const float* __restrict__ pBEV, const float* __restrict__ pB,
    float* __restrict__ partials)
{
    const int b      = blockIdx.x;
    const int t      = threadIdx.x;
    const int tensor = b >> 7;                 // 0..127 -> T0, 128..255 -> T1
    const int tb     = b & 127;
    const int tb21   = tb * TASKS_PER_BLOCK;   // first task (0..2687)
    const int wv     = t >> 6;
    const int lane   = t & 63;

    const float pb  = pB[0];
    const float bev = pBEV[0] * BEV[0];
    const float a   = -pb * 1.4426950408889634f;   // -pb*log2(e)
    const float ab  = a * bev;

    const float* Sb = tensor ? ST1 : ST0;
    const float* Wb = tensor ? W1  : W0;

    // block spans at most 2 rows (21 tasks, 32 tasks per row)
    const int r0 = tb21 >> 5;
    const int r1 = (tb21 + TASKS_PER_BLOCK - 1) >> 5;
    float pw0, pw1;
    if (tensor == 0) {
        pw0 = prob_entry(probs0, r0);
        pw1 = prob_entry(probs0, r1);
    } else {
        pw0 = prob_entry(probs1, r0) + prob_entry(probs2, r0)
            + prob_entry(probs3, r0) + prob_entry(probs4, r0);
        pw1 = prob_entry(probs1, r1) + prob_entry(probs2, r1)
            + prob_entry(probs3, r1) + prob_entry(probs4, r1);
    }

    // byte offset of this thread's k=0 float4 of task tb21
    const unsigned vbase = (unsigned)tb21 * TASK_BYTES
                         + (unsigned)wv * 4096u + (unsigned)lane * 16u;

    f32x4 vs0, vs1, vs2, vs3, vs4, vs5, vs6, vs7;   // S ring (8 pairs)
    f32x4 vw0, vw1, vw2, vw3, vw4, vw5, vw6, vw7;   // W ring

    float acc = 0.0f;

    // prologue: task 0 -> slots 0-3, task 1 -> slots 4-7 (16 loads in flight)
    ISSUE(vs0, vw0, 0 * TASK_BYTES + 0 * 1024);
    ISSUE(vs1, vw1, 0 * TASK_BYTES + 1 * 1024);
    ISSUE(vs2, vw2, 0 * TASK_BYTES + 2 * 1024);
    ISSUE(vs3, vw3, 0 * TASK_BYTES + 3 * 1024);
    ISSUE(vs4, vw4, 1 * TASK_BYTES + 0 * 1024);
    ISSUE(vs5, vw5, 1 * TASK_BYTES + 1 * 1024);
    ISSUE(vs6, vw6, 1 * TASK_BYTES + 2 * 1024);
    ISSUE(vs7, vw7, 1 * TASK_BYTES + 3 * 1024);

    // steady state: even tasks use slots 0-3, odd tasks slots 4-7
    TASK( 0, vs0,vw0,vs1,vw1,vs2,vw2,vs3,vw3, 14,14,14,14, 1);
    TASK( 1, vs4,vw4,vs5,vw5,vs6,vw6,vs7,vw7, 14,14,14,14, 1);
    TASK( 2, vs0,vw0,vs1,vw1,vs2,vw2,vs3,vw3, 14,14,14,14, 1);
    TASK( 3, vs4,vw4,vs5,vw5,vs6,vw6,vs7,vw7, 14,14,14,14, 1);
    TASK( 4, vs0,vw0,vs1,vw1,vs2,vw2,vs3,vw3, 14,14,14,14, 1);
    TASK( 5, vs4,vw4,vs5,vw5,vs6,vw6,vs7,vw7, 14,14,14,14, 1);
    TASK( 6, vs0,vw0,vs1,vw1,vs2,vw2,vs3,vw3, 14,14,14,14, 1);
    TASK( 7, vs4,vw4,vs5,vw5,vs6,vw6,vs7,vw7, 14,14,14,14, 1);
    TASK( 8, vs0,vw0,vs1,vw1,vs2,vw2,vs3,vw3, 14,14,14,14, 1);
    TASK( 9, vs4,vw4,vs5,vw5,vs6,vw6,vs7,vw7, 14,14,14,14, 1);
    TASK(10, vs0,vw0,vs1,vw1,vs2,vw2,vs3,vw3, 14,14,14,14, 1);
    TASK(11, vs4,vw4,vs5,vw5,vs6,vw6,vs7,vw7, 14,14,14,14, 1);
    TASK(12, vs0,vw0,vs1,vw1,vs2,vw2,vs3,vw3, 14,14,14,14, 1);
    TASK(13, vs4,vw4,vs5,vw5,vs6,vw6,vs7,vw7, 14,14,14,14, 1);
    TASK(14, vs0,vw0,vs1,vw1,vs2,vw2,vs3,vw3, 14,14,14,14, 1);
    TASK(15, vs4,vw4,vs5,vw5,vs6,vw6,vs7,vw7, 14,14,14,14, 1);
    TASK(16, vs0,vw0,vs1,vw1,vs2,vw2,vs3,vw3, 14,14,14,14, 1);
    TASK(17, vs4,vw4,vs5,vw5,vs6,vw6,vs7,vw7, 14,14,14,14, 1);
    TASK(18, vs0,vw0,vs1,vw1,vs2,vw2,vs3,vw3, 14,14,14,14, 1);
    // epilogue: all 84 pairs issued; taper the waits
    TASK(19, vs4,vw4,vs5,vw5,vs6,vw6,vs7,vw7, 14,12,10, 8, 0);
    TASK(20, vs0,vw0,vs1,vw1,vs2,vw2,vs3,vw3,  6, 4, 2, 0, 0);

    // wave64 shuffle reduction
    #pragma unroll
    for (int off = 32; off > 0; off >>= 1)
        acc += __shfl_down(acc, off, 64);

    __shared__ float red[4];
    if (lane == 0) red[wv] = acc;
    __syncthreads();

    if (t == 0)
        partials[b] = red[0] + red[1] + red[2] + red[3];
}

__global__ __launch_bounds__(256) void probsnet_reduce(
    const float* __restrict__ partials, float* __restrict__ out)
{
    const int t = threadIdx.x;
    float acc = partials[t];   // exactly 256 partials

    #pragma unroll
    for (int off = 32; off > 0; off >>= 1)
        acc += __shfl_down(acc, off, 64);

    __shared__ float red[4];
    const int wave = t >> 6;
    const int lane = t & 63;
    if (lane == 0) red[wave] = acc;
    __syncthreads();

    if (t == 0)
        out[0] = (red[0] + red[1] + red[2] + red[3]) * 0.2f;
}

extern "C" void kernel_launch(void* const* d_in, const int* in_sizes, int n_in,
                              void* d_out, int out_size, void* d_ws, size_t ws_size,
                              hipStream_t stream) {
    // setup_inputs order:
    // 0=BEV(1) 1=ST0 2=Weight0 3=ST1 4=Weight1 5=Problem(int,unused)
    // 6..10=probs0..probs4(4) 11=pBEV(1) 12=pB(1)
    const float* BEV    = (const float*)d_in[0];
    const float* ST0    = (const float*)d_in[1];
    const float* W0     = (const float*)d_in[2];
    const float* ST1    = (const float*)d_in[3];
    const float* W1     = (const float*)d_in[4];
    const float* probs0 = (const float*)d_in[6];
    const float* probs1 = (const float*)d_in[7];
    const float* probs2 = (const float*)d_in[8];
    const float* probs3 = (const float*)d_in[9];
    const float* probs4 = (const float*)d_in[10];
    const float* pBEV   = (const float*)d_in[11];
    const float* pB     = (const float*)d_in[12];

    float* partials = (float*)d_ws;          // 256 floats of scratch
    float* out      = (float*)d_out;

    probsnet_main<<<BLOCKS, 256, 0, stream>>>(
        BEV, ST0, W0, ST1, W1,
        probs0, probs1, probs2, probs3, probs4,
        pBEV, pB, partials);

    probsnet_reduce<<<1, 256, 0, stream>>>(partials, out);
}